// Round 6
// baseline (3319.431 us; speedup 1.0000x reference)
//
#include <hip/hip_runtime.h>
#include <hip/hip_bf16.h>
#include <cstdint>
#include <cstddef>

#define NN 50000
#define NE 300000
#define BN_EPS 1e-5f

typedef __hip_bfloat16 bf16;

__device__ __forceinline__ float to_f(float v) { return v; }
__device__ __forceinline__ float to_f(bf16 v) { return __bfloat162float(v); }
__device__ __forceinline__ void from_f(float& d, float v) { d = v; }
__device__ __forceinline__ void from_f(bf16& d, float v) { d = __float2bfloat16(v); }

// ---------------- degree count (int) ----------------
__global__ void deg_kernel(const int* __restrict__ dst, int* __restrict__ deg, int E) {
    int e = blockIdx.x * blockDim.x + threadIdx.x;
    if (e < E) atomicAdd(&deg[dst[e]], 1);
}

// ---------------- single-block exclusive scan + dis ----------------
__global__ void scan_kernel(const int* __restrict__ deg, int* __restrict__ rowstart,
                            float* __restrict__ dis, int n) {
    __shared__ int sh[256];
    __shared__ int carry_s;
    int tid = threadIdx.x;
    if (tid == 0) carry_s = 0;
    __syncthreads();
    for (int base = 0; base < n; base += 256) {
        int idx = base + tid;
        int v = (idx < n) ? deg[idx] : 0;
        if (idx < n) dis[idx] = rsqrtf((float)v + 1.0f);
        sh[tid] = v;
        __syncthreads();
        #pragma unroll
        for (int off = 1; off < 256; off <<= 1) {
            int t = (tid >= off) ? sh[tid - off] : 0;
            __syncthreads();
            sh[tid] += t;
            __syncthreads();
        }
        if (idx < n) rowstart[idx] = carry_s + sh[tid] - v;  // exclusive
        __syncthreads();
        if (tid == 255) carry_s += sh[255];
        __syncthreads();
    }
    if (tid == 0) rowstart[n] = carry_s;
}

// ---------------- CSR fill: slot edges by destination ----------------
__global__ void fill_kernel(const int* __restrict__ src, const int* __restrict__ dst,
                            const int* __restrict__ rowstart, int* __restrict__ cnt,
                            int* __restrict__ esrc, float* __restrict__ ew,
                            const float* __restrict__ dis, int E) {
    int e = blockIdx.x * blockDim.x + threadIdx.x;
    if (e >= E) return;
    int s = src[e], d = dst[e];
    int pos = rowstart[d] + atomicAdd(&cnt[d], 1);
    esrc[pos] = s;
    ew[pos] = dis[s] * dis[d];
}

// ---------------- gather aggregation: out[d] = sum_j w_j*pre(in[s_j]) + dis_d^2*pre(in[d]) (+bias)(+elu) ----------------
template <typename TI, typename TO>
__global__ __launch_bounds__(256) void gather_agg(
        const TI* __restrict__ in, TO* __restrict__ out,
        const int* __restrict__ rowstart, const int* __restrict__ esrc,
        const float* __restrict__ ew, const float* __restrict__ dis,
        const float* __restrict__ scale, const float* __restrict__ shift,
        const float* __restrict__ bias, int F, int do_elu) {
    int d = blockIdx.x;
    int j0 = rowstart[d], j1 = rowstart[d + 1];
    int f0 = threadIdx.x, f1 = threadIdx.x + 256;
    float dn = dis[d];
    float sw = dn * dn;
    float acc0 = 0.f, acc1 = 0.f;
    const TI* rowd = in + (size_t)d * F;
    if (f0 < F) {
        float v = to_f(rowd[f0]);
        if (scale) v = fmaf(v, scale[f0], shift[f0]);
        acc0 = v * sw;
    }
    if (f1 < F) {
        float v = to_f(rowd[f1]);
        if (scale) v = fmaf(v, scale[f1], shift[f1]);
        acc1 = v * sw;
    }
    for (int j = j0; j < j1; ++j) {
        int s = esrc[j];
        float w = ew[j];
        const TI* rows = in + (size_t)s * F;
        if (f0 < F) {
            float v = to_f(rows[f0]);
            if (scale) v = fmaf(v, scale[f0], shift[f0]);
            acc0 = fmaf(w, v, acc0);
        }
        if (f1 < F) {
            float v = to_f(rows[f1]);
            if (scale) v = fmaf(v, scale[f1], shift[f1]);
            acc1 = fmaf(w, v, acc1);
        }
    }
    if (f0 < F) {
        if (bias) acc0 += bias[f0];
        if (do_elu) acc0 = acc0 > 0.f ? acc0 : expm1f(acc0);
        from_f(out[(size_t)d * F + f0], acc0);
    }
    if (f1 < F) {
        if (bias) acc1 += bias[f1];
        if (do_elu) acc1 = acc1 > 0.f ? acc1 : expm1f(acc1);
        from_f(out[(size_t)d * F + f1], acc1);
    }
}

// ---------------- tiled GEMM: C = act(bn?(A) @ W + bias?) ----------------
#define BM 64
#define BNt 64
#define BK 16
template <typename TA, typename TC>
__global__ __launch_bounds__(256) void gemm_t(
        const TA* __restrict__ A, const float* __restrict__ W,
        const float* __restrict__ bias,
        const float* __restrict__ scale, const float* __restrict__ shift,
        TC* __restrict__ C,
        int M, int K, int Fout, int do_elu) {
    __shared__ float As[BK][BM + 4];
    __shared__ float Ws[BK][BNt];
    int bm = blockIdx.x * BM;
    int bn = blockIdx.y * BNt;
    int tid = threadIdx.x;
    int tr = tid >> 4, tc = tid & 15;
    float acc[4][4] = {};
    for (int k0 = 0; k0 < K; k0 += BK) {
        for (int l = tid; l < BM * BK; l += 256) {
            int r = l >> 4, c = l & 15;
            float v = 0.f;
            if (bm + r < M && k0 + c < K) {
                v = to_f(A[(size_t)(bm + r) * K + k0 + c]);
                if (scale) v = fmaf(v, scale[k0 + c], shift[k0 + c]);
            }
            As[c][r] = v;
        }
        for (int l = tid; l < BK * BNt; l += 256) {
            int r = l >> 6, c = l & 63;
            float v = 0.f;
            if (k0 + r < K && bn + c < Fout) v = W[(size_t)(k0 + r) * Fout + bn + c];
            Ws[r][c] = v;
        }
        __syncthreads();
        #pragma unroll
        for (int kk = 0; kk < BK; ++kk) {
            float a[4], w[4];
            #pragma unroll
            for (int i = 0; i < 4; ++i) a[i] = As[kk][tr * 4 + i];
            #pragma unroll
            for (int j = 0; j < 4; ++j) w[j] = Ws[kk][tc * 4 + j];
            #pragma unroll
            for (int i = 0; i < 4; ++i)
                #pragma unroll
                for (int j = 0; j < 4; ++j)
                    acc[i][j] = fmaf(a[i], w[j], acc[i][j]);
        }
        __syncthreads();
    }
    for (int i = 0; i < 4; ++i) {
        int r = bm + tr * 4 + i;
        if (r >= M) continue;
        for (int j = 0; j < 4; ++j) {
            int c = bn + tc * 4 + j;
            if (c >= Fout) continue;
            float v = acc[i][j];
            if (bias) v += bias[c];
            if (do_elu) v = v > 0.f ? v : expm1f(v);
            from_f(C[(size_t)r * Fout + c], v);
        }
    }
}

// ---------------- column stats over bf16 matrix ----------------
#define CS_ROWS 128
__global__ void colstats_kernel(const bf16* __restrict__ h, float* __restrict__ sum,
                                float* __restrict__ sumsq, int M, int F) {
    int r0 = blockIdx.x * CS_ROWS;
    int tid = threadIdx.x;  // 256
    float s[4] = {0.f, 0.f, 0.f, 0.f}, q[4] = {0.f, 0.f, 0.f, 0.f};
    int rend = min(r0 + CS_ROWS, M);
    for (int r = r0; r < rend; ++r) {
        #pragma unroll
        for (int j = 0; j < 4; ++j) {
            int c = tid + j * 256;
            if (c < F) {
                float v = to_f(h[(size_t)r * F + c]);
                s[j] += v;
                q[j] += v * v;
            }
        }
    }
    #pragma unroll
    for (int j = 0; j < 4; ++j) {
        int c = tid + j * 256;
        if (c < F) {
            atomicAdd(&sum[c], s[j]);
            atomicAdd(&sumsq[c], q[j]);
        }
    }
}

__global__ void bnparams_kernel(const float* __restrict__ sum, const float* __restrict__ sumsq,
                                const float* __restrict__ g, const float* __restrict__ be,
                                float* __restrict__ scale, float* __restrict__ shift,
                                int F, float invN) {
    int c = blockIdx.x * blockDim.x + threadIdx.x;
    if (c >= F) return;
    float m = sum[c] * invN;
    float v = sumsq[c] * invN - m * m;
    if (v < 0.f) v = 0.f;
    float sc = g[c] * rsqrtf(v + BN_EPS);
    scale[c] = sc;
    shift[c] = be[c] - m * sc;
}

extern "C" void kernel_launch(void* const* d_in, const int* in_sizes, int n_in,
                              void* d_out, int out_size, void* d_ws, size_t ws_size,
                              hipStream_t stream) {
    const float* x  = (const float*)d_in[0];
    const int* src  = (const int*)d_in[1];
    const int* dst  = (const int*)d_in[2];
    const float* W1 = (const float*)d_in[3];
    const float* b1 = (const float*)d_in[4];
    const float* g1 = (const float*)d_in[5];
    const float* be1= (const float*)d_in[6];
    const float* W2 = (const float*)d_in[7];
    const float* b2 = (const float*)d_in[8];
    const float* g2 = (const float*)d_in[9];
    const float* be2= (const float*)d_in[10];
    const float* W3 = (const float*)d_in[11];
    const float* b3 = (const float*)d_in[12];
    const float* g3 = (const float*)d_in[13];
    const float* be3= (const float*)d_in[14];
    const float* W4 = (const float*)d_in[15];
    const float* b4 = (const float*)d_in[16];
    float* out = (float*)d_out;

    char* ws = (char*)d_ws;
    // ---- workspace map ----
    // header:
    //   [0.0, 0.2) MiB  deg      (N ints)
    //   [0.2, 0.4) MiB  cnt      (N ints)
    //   [0.4, 0.6) MiB  rowstart (N+1 ints)
    //   [0.6, 0.8) MiB  dis      (N f32)
    //   [0.8, 0.87) MiB sum/sumsq/scale/shift (4×4096 f32)
    //   [1.00, 2.15) MiB esrc    (E ints = 1.145 MiB)
    //   [2.25, 3.40) MiB ew      (E f32  = 1.145 MiB)   <- was 2.0 MiB: OVERLAPPED esrc (r2/r5 crash)
    // big regions, lifetime-aliased, at 4 MiB. Total: 4 + 150 MiB.
    //   A  (50 MiB): aggX -> t2 -> t3 -> t4
    //   BC (100 MiB): h1 (first 50) -> h2 (all 100) -> h3 (first 50)
    // h1 dead before h2 written (consumed by t2 gather); h2 dead before h3
    // written (consumed by t3 GEMM). Single stream => ordered.
    int*   deg      = (int*)ws;
    int*   cnt      = deg + NN;
    int*   rowstart = cnt + NN;
    float* dis      = (float*)(rowstart + NN + 1);
    float* sum      = (float*)(ws + (800 << 10));
    float* sumsq    = sum + 4096;
    float* scale    = sum + 8192;
    float* shift    = sum + 12288;
    int*   esrc     = (int*)(ws + (1 << 20));
    float* ew       = (float*)(ws + 2359296);            // 2.25 MiB
    char* base = ws + (4u << 20);
    const size_t R50 = 52428800;                         // 50 MiB
    bf16* regA = (bf16*)base;
    bf16* regBC = (bf16*)(base + R50);

    // Defensive: if workspace is smaller than our 154 MiB plan, do nothing.
    // (Clean absmax failure beats an OOB container crash; diagnostic signal.)
    if (ws_size < (4u << 20) + 3 * R50) return;

    const float invN = 1.0f / (float)NN;

    // ---- CSR build ----
    hipMemsetAsync(deg, 0, 2 * NN * sizeof(int), stream);  // deg + cnt
    deg_kernel<<<(NE + 255) / 256, 256, 0, stream>>>(dst, deg, NE);
    scan_kernel<<<1, 256, 0, stream>>>(deg, rowstart, dis, NN);
    fill_kernel<<<(NE + 255) / 256, 256, 0, stream>>>(src, dst, rowstart, cnt, esrc, ew, dis, NE);

    // ---- Layer 1: aggX = A_hat x (F=128); h1 = elu(aggX W1 + b1) ----
    gather_agg<float, bf16><<<NN, 256, 0, stream>>>(
        x, regA, rowstart, esrc, ew, dis, nullptr, nullptr, nullptr, 128, 0);
    {
        dim3 g((NN + BM - 1) / BM, (500 + BNt - 1) / BNt);
        gemm_t<bf16, bf16><<<g, 256, 0, stream>>>(regA, W1, b1, nullptr, nullptr, regBC, NN, 128, 500, 1);
    }
    hipMemsetAsync(sum, 0, 8192 * sizeof(float), stream);
    colstats_kernel<<<(NN + CS_ROWS - 1) / CS_ROWS, 256, 0, stream>>>(regBC, sum, sumsq, NN, 500);
    bnparams_kernel<<<2, 256, 0, stream>>>(sum, sumsq, g1, be1, scale, shift, 500, invN);

    // ---- Layer 2: t2 = A_hat bn(h1) (F=500); h2 = elu(t2 W2 + b2) ----
    gather_agg<bf16, bf16><<<NN, 256, 0, stream>>>(
        regBC, regA, rowstart, esrc, ew, dis, scale, shift, nullptr, 500, 0);
    {
        dim3 g((NN + BM - 1) / BM, (1000 + BNt - 1) / BNt);
        gemm_t<bf16, bf16><<<g, 256, 0, stream>>>(regA, W2, b2, nullptr, nullptr, regBC, NN, 500, 1000, 1);
    }
    hipMemsetAsync(sum, 0, 8192 * sizeof(float), stream);
    colstats_kernel<<<(NN + CS_ROWS - 1) / CS_ROWS, 256, 0, stream>>>(regBC, sum, sumsq, NN, 1000);
    bnparams_kernel<<<4, 256, 0, stream>>>(sum, sumsq, g2, be2, scale, shift, 1000, invN);

    // ---- Layer 3: t3 = bn(h2) W3 (1000->500); h3 = elu(A_hat t3 + b3) ----
    {
        dim3 g((NN + BM - 1) / BM, (500 + BNt - 1) / BNt);
        gemm_t<bf16, bf16><<<g, 256, 0, stream>>>(regBC, W3, nullptr, scale, shift, regA, NN, 1000, 500, 0);
    }
    gather_agg<bf16, bf16><<<NN, 256, 0, stream>>>(
        regA, regBC, rowstart, esrc, ew, dis, nullptr, nullptr, b3, 500, 1);
    hipMemsetAsync(sum, 0, 8192 * sizeof(float), stream);
    colstats_kernel<<<(NN + CS_ROWS - 1) / CS_ROWS, 256, 0, stream>>>(regBC, sum, sumsq, NN, 500);
    bnparams_kernel<<<2, 256, 0, stream>>>(sum, sumsq, g3, be3, scale, shift, 500, invN);

    // ---- Layer 4: t4 = bn(h3) W4 (500->50) f32; out = A_hat t4 + b4 ----
    float* t4 = (float*)regA;  // 10 MB, region A free
    {
        dim3 g((NN + BM - 1) / BM, 1);
        gemm_t<bf16, float><<<g, 256, 0, stream>>>(regBC, W4, nullptr, scale, shift, t4, NN, 500, 50, 0);
    }
    gather_agg<float, float><<<NN, 256, 0, stream>>>(
        t4, out, rowstart, esrc, ew, dis, nullptr, nullptr, b4, 50, 0);
}

// Round 7
// 1668.368 us; speedup vs baseline: 1.9896x; 1.9896x over previous
//
#include <hip/hip_runtime.h>
#include <hip/hip_bf16.h>
#include <cstdint>
#include <cstddef>

#define NN 50000
#define NE 300000
#define BN_EPS 1e-5f

typedef unsigned short ushort_t;
typedef __attribute__((ext_vector_type(8))) short short8;
typedef __attribute__((ext_vector_type(4))) float f32x4;

// bf16 <-> f32 via bit ops (RNE), avoids __hip_bfloat16 ctor issues in unions/LDS
__device__ __forceinline__ float bf_to_f(ushort_t u) {
    union { unsigned int i; float f; } c; c.i = ((unsigned int)u) << 16; return c.f;
}
__device__ __forceinline__ ushort_t f_to_bf(float f) {
    union { unsigned int i; float f; } c; c.f = f;
    unsigned int r = c.i + 0x7FFF + ((c.i >> 16) & 1);
    return (ushort_t)(r >> 16);
}

__device__ __forceinline__ float to_f(float v) { return v; }
__device__ __forceinline__ float to_f(ushort_t v) { return bf_to_f(v); }
__device__ __forceinline__ void from_f(float& d, float v) { d = v; }
__device__ __forceinline__ void from_f(ushort_t& d, float v) { d = f_to_bf(v); }

// ---------------- degree count (int) ----------------
__global__ void deg_kernel(const int* __restrict__ dst, int* __restrict__ deg, int E) {
    int e = blockIdx.x * blockDim.x + threadIdx.x;
    if (e < E) atomicAdd(&deg[dst[e]], 1);
}

// ---------------- single-block exclusive scan + dis ----------------
__global__ void scan_kernel(const int* __restrict__ deg, int* __restrict__ rowstart,
                            float* __restrict__ dis, int n) {
    __shared__ int sh[256];
    __shared__ int carry_s;
    int tid = threadIdx.x;
    if (tid == 0) carry_s = 0;
    __syncthreads();
    for (int base = 0; base < n; base += 256) {
        int idx = base + tid;
        int v = (idx < n) ? deg[idx] : 0;
        if (idx < n) dis[idx] = rsqrtf((float)v + 1.0f);
        sh[tid] = v;
        __syncthreads();
        #pragma unroll
        for (int off = 1; off < 256; off <<= 1) {
            int t = (tid >= off) ? sh[tid - off] : 0;
            __syncthreads();
            sh[tid] += t;
            __syncthreads();
        }
        if (idx < n) rowstart[idx] = carry_s + sh[tid] - v;  // exclusive
        __syncthreads();
        if (tid == 255) carry_s += sh[255];
        __syncthreads();
    }
    if (tid == 0) rowstart[n] = carry_s;
}

// ---------------- CSR fill: slot edges by destination ----------------
__global__ void fill_kernel(const int* __restrict__ src, const int* __restrict__ dst,
                            const int* __restrict__ rowstart, int* __restrict__ cnt,
                            int* __restrict__ esrc, float* __restrict__ ew,
                            const float* __restrict__ dis, int E) {
    int e = blockIdx.x * blockDim.x + threadIdx.x;
    if (e >= E) return;
    int s = src[e], d = dst[e];
    int pos = rowstart[d] + atomicAdd(&cnt[d], 1);
    esrc[pos] = s;
    ew[pos] = dis[s] * dis[d];
}

// ---------------- W transpose+convert: W[K][N] f32 -> WT[NP][KP] bf16, zero-padded ----------------
__global__ void wt_kernel(const float* __restrict__ W, ushort_t* __restrict__ WT,
                          int K, int N, int KP, int NP) {
    int i = blockIdx.x * 256 + threadIdx.x;
    int total = NP * KP;
    if (i >= total) return;
    int n = i / KP, k = i - n * KP;
    float v = (k < K && n < N) ? W[(size_t)k * N + n] : 0.f;
    WT[i] = f_to_bf(v);
}

// ---------------- gather aggregation (strided/padded) ----------------
// out[d,f] = sum_j ew_j*pre(in[s_j,f]) + dis_d^2*pre(in[d,f]) (+bias)(+elu), f<F
// out[d,f] = 0 for F<=f<FPout (keep pads zero for downstream MFMA GEMM)
template <typename TI, typename TO>
__global__ __launch_bounds__(256) void gather_agg(
        const TI* __restrict__ in, TO* __restrict__ out,
        const int* __restrict__ rowstart, const int* __restrict__ esrc,
        const float* __restrict__ ew, const float* __restrict__ dis,
        const float* __restrict__ scale, const float* __restrict__ shift,
        const float* __restrict__ bias, int F, int FPin, int FPout, int do_elu) {
    int d = blockIdx.x;
    int j0 = rowstart[d], j1 = rowstart[d + 1];
    int f0 = threadIdx.x, f1 = threadIdx.x + 256;
    bool c0 = f0 < F, c1 = f1 < F;
    float dn = dis[d];
    float sw = dn * dn;
    float acc0 = 0.f, acc1 = 0.f;
    const TI* rowd = in + (size_t)d * FPin;
    if (c0) {
        float v = to_f(rowd[f0]);
        if (scale) v = fmaf(v, scale[f0], shift[f0]);
        acc0 = v * sw;
    }
    if (c1) {
        float v = to_f(rowd[f1]);
        if (scale) v = fmaf(v, scale[f1], shift[f1]);
        acc1 = v * sw;
    }
    for (int j = j0; j < j1; ++j) {
        int s = esrc[j];
        float w = ew[j];
        const TI* rows = in + (size_t)s * FPin;
        if (c0) {
            float v = to_f(rows[f0]);
            if (scale) v = fmaf(v, scale[f0], shift[f0]);
            acc0 = fmaf(w, v, acc0);
        }
        if (c1) {
            float v = to_f(rows[f1]);
            if (scale) v = fmaf(v, scale[f1], shift[f1]);
            acc1 = fmaf(w, v, acc1);
        }
    }
    if (f0 < FPout) {
        float v = 0.f;
        if (c0) {
            v = acc0;
            if (bias) v += bias[f0];
            if (do_elu) v = v > 0.f ? v : expm1f(v);
        }
        from_f(out[(size_t)d * FPout + f0], v);
    }
    if (f1 < FPout) {
        float v = 0.f;
        if (c1) {
            v = acc1;
            if (bias) v += bias[f1];
            if (do_elu) v = v > 0.f ? v : expm1f(v);
        }
        from_f(out[(size_t)d * FPout + f1], v);
    }
}

// ---------------- MFMA GEMM: C = act(bn?(A) @ W + bias?) ----------------
// A: bf16 [M][KP] (pads zero), WT: bf16 [NP][KP] (pads zero), C: [M][CP]
// 128x64 tile, 4 waves (2x2), each wave 64x32 = 4x2 frags of 16x16, K-step 32.
template <typename TC>
__global__ __launch_bounds__(256) void mfma_gemm(
        const ushort_t* __restrict__ A, const ushort_t* __restrict__ WT,
        const float* __restrict__ bias,
        const float* __restrict__ scale, const float* __restrict__ shift,
        TC* __restrict__ C,
        int M, int KP, int N, int CP, int do_elu) {
    __shared__ ushort_t As[128][40];   // +8 pad: 80B row stride, 16B-aligned slots
    __shared__ ushort_t Bs[64][40];
    int bm = blockIdx.x * 128;
    int bn = blockIdx.y * 64;
    int tid = threadIdx.x;
    int lane = tid & 63, wid = tid >> 6;
    int wr = wid >> 1, wc = wid & 1;
    int rl = lane & 15, kg = lane >> 4;
    f32x4 acc[4][2] = {};

    for (int k0 = 0; k0 < KP; k0 += 32) {
        // stage A: 128 rows x 32 k = 512 slots of 8 bf16 (16B)
        #pragma unroll
        for (int it = 0; it < 2; ++it) {
            int s = tid + it * 256;
            int r = s >> 2, q = s & 3;
            int grow = bm + r;
            union { int4 v; ushort_t h[8]; } u;
            if (grow < M) u.v = *(const int4*)(A + (size_t)grow * KP + k0 + q * 8);
            else u.v = make_int4(0, 0, 0, 0);
            if (scale) {
                #pragma unroll
                for (int j = 0; j < 8; ++j) {
                    int k = k0 + q * 8 + j;
                    u.h[j] = f_to_bf(fmaf(bf_to_f(u.h[j]), scale[k], shift[k]));
                }
            }
            *(int4*)&As[r][q * 8] = u.v;
        }
        // stage B: 64 rows x 32 k = 256 slots
        {
            int r = tid >> 2, q = tid & 3;
            *(int4*)&Bs[r][q * 8] = *(const int4*)(WT + (size_t)(bn + r) * KP + k0 + q * 8);
        }
        __syncthreads();
        short8 av[4], bv[2];
        #pragma unroll
        for (int mi = 0; mi < 4; ++mi)
            av[mi] = *(const short8*)&As[wr * 64 + mi * 16 + rl][kg * 8];
        #pragma unroll
        for (int ni = 0; ni < 2; ++ni)
            bv[ni] = *(const short8*)&Bs[wc * 32 + ni * 16 + rl][kg * 8];
        #pragma unroll
        for (int mi = 0; mi < 4; ++mi)
            #pragma unroll
            for (int ni = 0; ni < 2; ++ni)
                acc[mi][ni] = __builtin_amdgcn_mfma_f32_16x16x32_bf16(
                    av[mi], bv[ni], acc[mi][ni], 0, 0, 0);
        __syncthreads();
    }
    // epilogue: D row = (lane>>4)*4 + r, col = lane&15 (m89-verified layout)
    #pragma unroll
    for (int mi = 0; mi < 4; ++mi) {
        #pragma unroll
        for (int ni = 0; ni < 2; ++ni) {
            int col = bn + wc * 32 + ni * 16 + rl;
            #pragma unroll
            for (int r = 0; r < 4; ++r) {
                int row = bm + wr * 64 + mi * 16 + kg * 4 + r;
                if (row >= M) continue;
                float v = 0.f;
                if (col < N) {
                    v = acc[mi][ni][r];
                    if (bias) v += bias[col];
                    if (do_elu) v = v > 0.f ? v : expm1f(v);
                }
                from_f(C[(size_t)row * CP + col], v);  // col>=N: keep pad zero
            }
        }
    }
}

// ---------------- column stats over strided bf16 matrix ----------------
#define CS_ROWS 128
__global__ void colstats_kernel(const ushort_t* __restrict__ h, float* __restrict__ sum,
                                float* __restrict__ sumsq, int M, int F, int FP) {
    int r0 = blockIdx.x * CS_ROWS;
    int tid = threadIdx.x;  // 256
    float s[4] = {0.f, 0.f, 0.f, 0.f}, q[4] = {0.f, 0.f, 0.f, 0.f};
    int rend = min(r0 + CS_ROWS, M);
    for (int r = r0; r < rend; ++r) {
        #pragma unroll
        for (int j = 0; j < 4; ++j) {
            int c = tid + j * 256;
            if (c < F) {
                float v = bf_to_f(h[(size_t)r * FP + c]);
                s[j] += v;
                q[j] += v * v;
            }
        }
    }
    #pragma unroll
    for (int j = 0; j < 4; ++j) {
        int c = tid + j * 256;
        if (c < F) {
            atomicAdd(&sum[c], s[j]);
            atomicAdd(&sumsq[c], q[j]);
        }
    }
}

__global__ void bnparams_kernel(const float* __restrict__ sum, const float* __restrict__ sumsq,
                                const float* __restrict__ g, const float* __restrict__ be,
                                float* __restrict__ scale, float* __restrict__ shift,
                                int F, float invN) {
    int c = blockIdx.x * blockDim.x + threadIdx.x;
    if (c >= F) return;
    float m = sum[c] * invN;
    float v = sumsq[c] * invN - m * m;
    if (v < 0.f) v = 0.f;
    float sc = g[c] * rsqrtf(v + BN_EPS);
    scale[c] = sc;
    shift[c] = be[c] - m * sc;
}

extern "C" void kernel_launch(void* const* d_in, const int* in_sizes, int n_in,
                              void* d_out, int out_size, void* d_ws, size_t ws_size,
                              hipStream_t stream) {
    const float* x  = (const float*)d_in[0];
    const int* src  = (const int*)d_in[1];
    const int* dst  = (const int*)d_in[2];
    const float* W1 = (const float*)d_in[3];
    const float* b1 = (const float*)d_in[4];
    const float* g1 = (const float*)d_in[5];
    const float* be1= (const float*)d_in[6];
    const float* W2 = (const float*)d_in[7];
    const float* b2 = (const float*)d_in[8];
    const float* g2 = (const float*)d_in[9];
    const float* be2= (const float*)d_in[10];
    const float* W3 = (const float*)d_in[11];
    const float* b3 = (const float*)d_in[12];
    const float* g3 = (const float*)d_in[13];
    const float* be3= (const float*)d_in[14];
    const float* W4 = (const float*)d_in[15];
    const float* b4 = (const float*)d_in[16];
    float* out = (float*)d_out;

    char* ws = (char*)d_ws;
    // header layout (disjoint; esrc/ew overlap bug fixed in r5):
    int*   deg      = (int*)ws;                          // [0.0,0.2) MiB
    int*   cnt      = deg + NN;                          // [0.2,0.4)
    int*   rowstart = cnt + NN;                          // [0.4,0.6)
    float* dis      = (float*)(rowstart + NN + 1);       // [0.6,0.8)
    float* sum      = (float*)(ws + (800 << 10));        // [0.8,0.87)
    float* sumsq    = sum + 4096;
    float* scale    = sum + 8192;
    float* shift    = sum + 12288;
    int*   esrc     = (int*)(ws + (1 << 20));            // [1.00,2.15) MiB
    float* ew       = (float*)(ws + 2359296);            // [2.25,3.40) MiB
    // WT buffers [4,8) MiB
    ushort_t* wt1 = (ushort_t*)(ws + (4u << 20));        // 512x128x2  = 128 KB
    ushort_t* wt2 = (ushort_t*)(ws + (4u << 20) + (512u << 10));   // 1024x512x2 = 1 MB
    ushort_t* wt3 = (ushort_t*)(ws + (4u << 20) + (1664u << 10));  // 512x1024x2 = 1 MB
    ushort_t* wt4 = (ushort_t*)(ws + (4u << 20) + (2816u << 10));  // 64x512x2   = 64 KB
    // big regions at 8 MiB, lifetime-aliased:
    //   A  (50 MiB): aggX[M][128] -> t2[M][512] -> t3[M][512] -> t4 f32[M][64]
    //   BC (100 MiB): h1[M][512] -> h2[M][1024] -> h3[M][512]
    char* base = ws + (8u << 20);
    const size_t R50 = 52428800;
    ushort_t* regA  = (ushort_t*)base;
    ushort_t* regBC = (ushort_t*)(base + R50);

    if (ws_size < (8u << 20) + 3 * R50) return;  // clean fail > OOB crash

    const float invN = 1.0f / (float)NN;

    // ---- CSR build + W transposes ----
    hipMemsetAsync(deg, 0, 2 * NN * sizeof(int), stream);  // deg + cnt
    deg_kernel<<<(NE + 255) / 256, 256, 0, stream>>>(dst, deg, NE);
    scan_kernel<<<1, 256, 0, stream>>>(deg, rowstart, dis, NN);
    fill_kernel<<<(NE + 255) / 256, 256, 0, stream>>>(src, dst, rowstart, cnt, esrc, ew, dis, NE);
    wt_kernel<<<(512 * 128 + 255) / 256, 256, 0, stream>>>(W1, wt1, 128, 500, 128, 512);
    wt_kernel<<<(1024 * 512 + 255) / 256, 256, 0, stream>>>(W2, wt2, 500, 1000, 512, 1024);
    wt_kernel<<<(512 * 1024 + 255) / 256, 256, 0, stream>>>(W3, wt3, 1000, 500, 1024, 512);
    wt_kernel<<<(64 * 512 + 255) / 256, 256, 0, stream>>>(W4, wt4, 500, 50, 512, 64);

    const int GM = (NN + 127) / 128;  // 391

    // ---- Layer 1: aggX = A_hat x (F=128); h1 = elu(aggX W1 + b1) ----
    gather_agg<float, ushort_t><<<NN, 256, 0, stream>>>(
        x, regA, rowstart, esrc, ew, dis, nullptr, nullptr, nullptr, 128, 128, 128, 0);
    mfma_gemm<ushort_t><<<dim3(GM, 8), 256, 0, stream>>>(
        regA, wt1, b1, nullptr, nullptr, regBC, NN, 128, 500, 512, 1);
    hipMemsetAsync(sum, 0, 8192 * sizeof(float), stream);
    colstats_kernel<<<(NN + CS_ROWS - 1) / CS_ROWS, 256, 0, stream>>>(regBC, sum, sumsq, NN, 500, 512);
    bnparams_kernel<<<2, 256, 0, stream>>>(sum, sumsq, g1, be1, scale, shift, 500, invN);

    // ---- Layer 2: t2 = A_hat bn(h1); h2 = elu(t2 W2 + b2) ----
    gather_agg<ushort_t, ushort_t><<<NN, 256, 0, stream>>>(
        regBC, regA, rowstart, esrc, ew, dis, scale, shift, nullptr, 500, 512, 512, 0);
    mfma_gemm<ushort_t><<<dim3(GM, 16), 256, 0, stream>>>(
        regA, wt2, b2, nullptr, nullptr, regBC, NN, 512, 1000, 1024, 1);
    hipMemsetAsync(sum, 0, 8192 * sizeof(float), stream);
    colstats_kernel<<<(NN + CS_ROWS - 1) / CS_ROWS, 256, 0, stream>>>(regBC, sum, sumsq, NN, 1000, 1024);
    bnparams_kernel<<<4, 256, 0, stream>>>(sum, sumsq, g2, be2, scale, shift, 1000, invN);

    // ---- Layer 3: t3 = bn(h2) W3; h3 = elu(A_hat t3 + b3) ----
    mfma_gemm<ushort_t><<<dim3(GM, 8), 256, 0, stream>>>(
        regBC, wt3, nullptr, scale, shift, regA, NN, 1024, 500, 512, 0);
    gather_agg<ushort_t, ushort_t><<<NN, 256, 0, stream>>>(
        regA, regBC, rowstart, esrc, ew, dis, nullptr, nullptr, b3, 500, 512, 512, 1);
    hipMemsetAsync(sum, 0, 8192 * sizeof(float), stream);
    colstats_kernel<<<(NN + CS_ROWS - 1) / CS_ROWS, 256, 0, stream>>>(regBC, sum, sumsq, NN, 500, 512);
    bnparams_kernel<<<2, 256, 0, stream>>>(sum, sumsq, g3, be3, scale, shift, 500, invN);

    // ---- Layer 4: t4 = bn(h3) W4 (f32); out = A_hat t4 + b4 ----
    float* t4 = (float*)regA;  // [M][64] f32 = 12.8 MB
    mfma_gemm<float><<<dim3(GM, 1), 256, 0, stream>>>(
        regBC, wt4, nullptr, scale, shift, t4, NN, 512, 50, 64, 0);
    gather_agg<float, float><<<NN, 256, 0, stream>>>(
        t4, out, rowstart, esrc, ew, dis, nullptr, nullptr, b4, 50, 64, 50, 0);
}

// Round 9
// 1199.586 us; speedup vs baseline: 2.7671x; 1.3908x over previous
//
#include <hip/hip_runtime.h>
#include <hip/hip_bf16.h>
#include <cstdint>
#include <cstddef>

#define NN 50000
#define NE 300000
#define BN_EPS 1e-5f

typedef unsigned short ushort_t;
typedef __attribute__((ext_vector_type(8))) short short8;
typedef __attribute__((ext_vector_type(4))) float f32x4;

__device__ __forceinline__ float bf_to_f(ushort_t u) {
    union { unsigned int i; float f; } c; c.i = ((unsigned int)u) << 16; return c.f;
}
__device__ __forceinline__ ushort_t f_to_bf(float f) {
    union { unsigned int i; float f; } c; c.f = f;
    unsigned int r = c.i + 0x7FFF + ((c.i >> 16) & 1);
    return (ushort_t)(r >> 16);
}
__device__ __forceinline__ void from_f(float& d, float v) { d = v; }
__device__ __forceinline__ void from_f(ushort_t& d, float v) { d = f_to_bf(v); }

// ---------------- degree count ----------------
__global__ void deg_kernel(const int* __restrict__ dst, int* __restrict__ deg, int E) {
    int e = blockIdx.x * blockDim.x + threadIdx.x;
    if (e < E) atomicAdd(&deg[dst[e]], 1);
}

// ---------------- 3-phase device-wide exclusive scan ----------------
__global__ void scan_reduce(const int* __restrict__ deg, int* __restrict__ bsum,
                            float* __restrict__ dis, int n) {
    int tid = threadIdx.x;
    int idx = blockIdx.x * 256 + tid;
    int v = (idx < n) ? deg[idx] : 0;
    if (idx < n) dis[idx] = rsqrtf((float)v + 1.0f);
    __shared__ int sh[256];
    sh[tid] = v;
    __syncthreads();
    #pragma unroll
    for (int off = 128; off > 0; off >>= 1) {
        if (tid < off) sh[tid] += sh[tid + off];
        __syncthreads();
    }
    if (tid == 0) bsum[blockIdx.x] = sh[0];
}

__global__ void scan_offsets(const int* __restrict__ bsum, int* __restrict__ boff,
                             int* __restrict__ rowstart, int nb, int n) {
    __shared__ int sh[256];
    int tid = threadIdx.x;
    int v = (tid < nb) ? bsum[tid] : 0;
    sh[tid] = v;
    __syncthreads();
    #pragma unroll
    for (int off = 1; off < 256; off <<= 1) {
        int t = (tid >= off) ? sh[tid - off] : 0;
        __syncthreads();
        sh[tid] += t;
        __syncthreads();
    }
    if (tid < nb) boff[tid] = sh[tid] - v;   // exclusive
    if (tid == nb - 1) rowstart[n] = sh[tid];
}

__global__ void scan_final(const int* __restrict__ deg, const int* __restrict__ boff,
                           int* __restrict__ rowstart, int n) {
    int tid = threadIdx.x;
    int idx = blockIdx.x * 256 + tid;
    int v = (idx < n) ? deg[idx] : 0;
    __shared__ int sh[256];
    sh[tid] = v;
    __syncthreads();
    #pragma unroll
    for (int off = 1; off < 256; off <<= 1) {
        int t = (tid >= off) ? sh[tid - off] : 0;
        __syncthreads();
        sh[tid] += t;
        __syncthreads();
    }
    if (idx < n) rowstart[idx] = boff[blockIdx.x] + sh[tid] - v;
}

// ---------------- CSR fill ----------------
__global__ void fill_kernel(const int* __restrict__ src, const int* __restrict__ dst,
                            const int* __restrict__ rowstart, int* __restrict__ cnt,
                            int* __restrict__ esrc, float* __restrict__ ew,
                            const float* __restrict__ dis, int E) {
    int e = blockIdx.x * blockDim.x + threadIdx.x;
    if (e >= E) return;
    int s = src[e], d = dst[e];
    int pos = rowstart[d] + atomicAdd(&cnt[d], 1);
    esrc[pos] = s;
    ew[pos] = dis[s] * dis[d];
}

// ---------------- W transpose+convert ----------------
__global__ void wt_kernel(const float* __restrict__ W, ushort_t* __restrict__ WT,
                          int K, int N, int KP, int NP) {
    int i = blockIdx.x * 256 + threadIdx.x;
    int total = NP * KP;
    if (i >= total) return;
    int n = i / KP, k = i - n * KP;
    float v = (k < K && n < N) ? W[(size_t)k * N + n] : 0.f;
    WT[i] = f_to_bf(v);
}

// ---------------- wave-per-node gathers ----------------
// layer 1: x f32 [128] -> bf16 [128]. lane owns 2 cols (float2).
__global__ __launch_bounds__(256) void gather_x(
        const float* __restrict__ in, ushort_t* __restrict__ out,
        const int* __restrict__ rowstart, const int* __restrict__ esrc,
        const float* __restrict__ ew, const float* __restrict__ dis, int nnodes) {
    int gw = (blockIdx.x * 256 + threadIdx.x) >> 6;
    if (gw >= nnodes) return;
    int lane = threadIdx.x & 63;
    int c0 = lane * 2;
    int j0 = rowstart[gw], j1 = rowstart[gw + 1];
    float dn = dis[gw], sw = dn * dn;
    float2 v0 = *(const float2*)(in + (size_t)gw * 128 + c0);
    float a0 = v0.x * sw, a1 = v0.y * sw;
    for (int j = j0; j < j1; ++j) {
        int s = esrc[j];
        float w = ew[j];
        float2 u = *(const float2*)(in + (size_t)s * 128 + c0);
        a0 = fmaf(w, u.x, a0);
        a1 = fmaf(w, u.y, a1);
    }
    unsigned int packed = (unsigned int)f_to_bf(a0) | ((unsigned int)f_to_bf(a1) << 16);
    *(unsigned int*)(out + (size_t)gw * 128 + c0) = packed;
}

// layers 2/3: bf16 [512] -> bf16 [512], 8 cols/lane, optional bn, bias+elu.
__global__ __launch_bounds__(256) void gather_b8(
        const ushort_t* __restrict__ in, ushort_t* __restrict__ out,
        const int* __restrict__ rowstart, const int* __restrict__ esrc,
        const float* __restrict__ ew, const float* __restrict__ dis,
        const float* __restrict__ scale, const float* __restrict__ shift,
        const float* __restrict__ bias, int F, int do_elu, int nnodes) {
    int gw = (blockIdx.x * 256 + threadIdx.x) >> 6;
    if (gw >= nnodes) return;
    int lane = threadIdx.x & 63;
    int c0 = lane * 8;
    int j0 = rowstart[gw], j1 = rowstart[gw + 1];
    float dn = dis[gw], sw = dn * dn;
    float sc[8], sh[8], bs[8];
    #pragma unroll
    for (int k = 0; k < 8; ++k) {
        sc[k] = scale ? scale[c0 + k] : 1.f;     // pads zeroed by bnparams
        sh[k] = scale ? shift[c0 + k] : 0.f;
        bs[k] = (bias && c0 + k < F) ? bias[c0 + k] : 0.f;
    }
    float acc[8];
    {
        short8 u = *(const short8*)(in + (size_t)gw * 512 + c0);
        #pragma unroll
        for (int k = 0; k < 8; ++k)
            acc[k] = fmaf(bf_to_f((ushort_t)u[k]), sc[k], sh[k]) * sw;
    }
    for (int j = j0; j < j1; ++j) {
        int s = esrc[j];
        float w = ew[j];
        short8 u = *(const short8*)(in + (size_t)s * 512 + c0);
        #pragma unroll
        for (int k = 0; k < 8; ++k)
            acc[k] = fmaf(w, fmaf(bf_to_f((ushort_t)u[k]), sc[k], sh[k]), acc[k]);
    }
    short8 o;
    #pragma unroll
    for (int k = 0; k < 8; ++k) {
        float v = 0.f;
        if (c0 + k < F) {
            v = acc[k] + bs[k];
            if (do_elu) v = v > 0.f ? v : expm1f(v);
        }
        o[k] = (short)f_to_bf(v);
    }
    *(short8*)(out + (size_t)gw * 512 + c0) = o;
}

// layer 4: f32 [64] -> out f32 [50], + bias. lane owns 1 col.
__global__ __launch_bounds__(256) void gather_out(
        const float* __restrict__ in, float* __restrict__ out,
        const int* __restrict__ rowstart, const int* __restrict__ esrc,
        const float* __restrict__ ew, const float* __restrict__ dis,
        const float* __restrict__ bias, int nnodes) {
    int gw = (blockIdx.x * 256 + threadIdx.x) >> 6;
    if (gw >= nnodes) return;
    int lane = threadIdx.x & 63;
    int j0 = rowstart[gw], j1 = rowstart[gw + 1];
    float dn = dis[gw], sw = dn * dn;
    float a = 0.f;
    if (lane < 50) a = in[(size_t)gw * 64 + lane] * sw;
    for (int j = j0; j < j1; ++j) {
        int s = esrc[j];
        float w = ew[j];
        if (lane < 50) a = fmaf(w, in[(size_t)s * 64 + lane], a);
    }
    if (lane < 50) out[(size_t)gw * 50 + lane] = a + bias[lane];
}

// ---------------- MFMA GEMM: C = act(bn?(A) @ W + bias?) ----------------
template <typename TC>
__global__ __launch_bounds__(256) void mfma_gemm(
        const ushort_t* __restrict__ A, const ushort_t* __restrict__ WT,
        const float* __restrict__ bias,
        const float* __restrict__ scale, const float* __restrict__ shift,
        TC* __restrict__ C,
        int M, int KP, int N, int CP, int do_elu) {
    __shared__ ushort_t As[128][40];
    __shared__ ushort_t Bs[64][40];
    int bm = blockIdx.x * 128;
    int bn = blockIdx.y * 64;
    int tid = threadIdx.x;
    int lane = tid & 63, wid = tid >> 6;
    int wr = wid >> 1, wc = wid & 1;
    int rl = lane & 15, kg = lane >> 4;
    f32x4 acc[4][2] = {};

    for (int k0 = 0; k0 < KP; k0 += 32) {
        #pragma unroll
        for (int it = 0; it < 2; ++it) {
            int s = tid + it * 256;
            int r = s >> 2, q = s & 3;
            int grow = bm + r;
            union { int4 v; ushort_t h[8]; } u;
            if (grow < M) u.v = *(const int4*)(A + (size_t)grow * KP + k0 + q * 8);
            else u.v = make_int4(0, 0, 0, 0);
            if (scale) {
                #pragma unroll
                for (int j = 0; j < 8; ++j) {
                    int k = k0 + q * 8 + j;
                    u.h[j] = f_to_bf(fmaf(bf_to_f(u.h[j]), scale[k], shift[k]));
                }
            }
            *(int4*)&As[r][q * 8] = u.v;
        }
        {
            int r = tid >> 2, q = tid & 3;
            *(int4*)&Bs[r][q * 8] = *(const int4*)(WT + (size_t)(bn + r) * KP + k0 + q * 8);
        }
        __syncthreads();
        short8 av[4], bv[2];
        #pragma unroll
        for (int mi = 0; mi < 4; ++mi)
            av[mi] = *(const short8*)&As[wr * 64 + mi * 16 + rl][kg * 8];
        #pragma unroll
        for (int ni = 0; ni < 2; ++ni)
            bv[ni] = *(const short8*)&Bs[wc * 32 + ni * 16 + rl][kg * 8];
        #pragma unroll
        for (int mi = 0; mi < 4; ++mi)
            #pragma unroll
            for (int ni = 0; ni < 2; ++ni)
                acc[mi][ni] = __builtin_amdgcn_mfma_f32_16x16x32_bf16(
                    av[mi], bv[ni], acc[mi][ni], 0, 0, 0);
        __syncthreads();
    }
    #pragma unroll
    for (int mi = 0; mi < 4; ++mi) {
        #pragma unroll
        for (int ni = 0; ni < 2; ++ni) {
            int col = bn + wc * 32 + ni * 16 + rl;
            #pragma unroll
            for (int r = 0; r < 4; ++r) {
                int row = bm + wr * 64 + mi * 16 + kg * 4 + r;
                if (row >= M) continue;
                float v = 0.f;
                if (col < N) {
                    v = acc[mi][ni][r];
                    if (bias) v += bias[col];
                    if (do_elu) v = v > 0.f ? v : expm1f(v);
                }
                from_f(C[(size_t)row * CP + col], v);
            }
        }
    }
}

// ---------------- column stats ----------------
#define CS_ROWS 128
__global__ void colstats_kernel(const ushort_t* __restrict__ h, float* __restrict__ sum,
                                float* __restrict__ sumsq, int M, int F, int FP) {
    int r0 = blockIdx.x * CS_ROWS;
    int tid = threadIdx.x;
    float s[4] = {0.f, 0.f, 0.f, 0.f}, q[4] = {0.f, 0.f, 0.f, 0.f};
    int rend = min(r0 + CS_ROWS, M);
    for (int r = r0; r < rend; ++r) {
        #pragma unroll
        for (int j = 0; j < 4; ++j) {
            int c = tid + j * 256;
            if (c < F) {
                float v = bf_to_f(h[(size_t)r * FP + c]);
                s[j] += v;
                q[j] += v * v;
            }
        }
    }
    #pragma unroll
    for (int j = 0; j < 4; ++j) {
        int c = tid + j * 256;
        if (c < F) {
            atomicAdd(&sum[c], s[j]);
            atomicAdd(&sumsq[c], q[j]);
        }
    }
}

// zero pad cols [F, FP) so downstream padded reads are well-defined
__global__ void bnparams_kernel(const float* __restrict__ sum, const float* __restrict__ sumsq,
                                const float* __restrict__ g, const float* __restrict__ be,
                                float* __restrict__ scale, float* __restrict__ shift,
                                int F, int FP, float invN) {
    int c = blockIdx.x * blockDim.x + threadIdx.x;
    if (c >= FP) return;
    if (c >= F) { scale[c] = 0.f; shift[c] = 0.f; return; }
    float m = sum[c] * invN;
    float v = sumsq[c] * invN - m * m;
    if (v < 0.f) v = 0.f;
    float sc = g[c] * rsqrtf(v + BN_EPS);
    scale[c] = sc;
    shift[c] = be[c] - m * sc;
}

extern "C" void kernel_launch(void* const* d_in, const int* in_sizes, int n_in,
                              void* d_out, int out_size, void* d_ws, size_t ws_size,
                              hipStream_t stream) {
    const float* x  = (const float*)d_in[0];
    const int* src  = (const int*)d_in[1];
    const int* dst  = (const int*)d_in[2];
    const float* W1 = (const float*)d_in[3];
    const float* b1 = (const float*)d_in[4];
    const float* g1 = (const float*)d_in[5];
    const float* be1= (const float*)d_in[6];
    const float* W2 = (const float*)d_in[7];
    const float* b2 = (const float*)d_in[8];
    const float* g2 = (const float*)d_in[9];
    const float* be2= (const float*)d_in[10];
    const float* W3 = (const float*)d_in[11];
    const float* b3 = (const float*)d_in[12];
    const float* g3 = (const float*)d_in[13];
    const float* be3= (const float*)d_in[14];
    const float* W4 = (const float*)d_in[15];
    const float* b4 = (const float*)d_in[16];
    float* out = (float*)d_out;

    char* ws = (char*)d_ws;
    int*   deg      = (int*)ws;                          // [0.0,0.2) MiB
    int*   cnt      = deg + NN;                          // [0.2,0.4)
    int*   rowstart = cnt + NN;                          // [0.4,0.6)
    float* dis      = (float*)(rowstart + NN + 1);       // [0.6,0.8)
    float* sum      = (float*)(ws + (800 << 10));
    float* sumsq    = sum + 4096;
    float* scale    = sum + 8192;
    float* shift    = sum + 12288;
    int*   bsum     = (int*)(shift + 4096);              // 256 ints (scan partials)
    int*   boff     = bsum + 256;                        // 256 ints
    int*   esrc     = (int*)(ws + (1 << 20));            // [1.00,2.15) MiB
    float* ew       = (float*)(ws + 2359296);            // [2.25,3.40) MiB
    ushort_t* wt1 = (ushort_t*)(ws + (4u << 20));
    ushort_t* wt2 = (ushort_t*)(ws + (4u << 20) + (512u << 10));
    ushort_t* wt3 = (ushort_t*)(ws + (4u << 20) + (1664u << 10));
    ushort_t* wt4 = (ushort_t*)(ws + (4u << 20) + (2816u << 10));
    char* base = ws + (8u << 20);
    const size_t R50 = 52428800;
    ushort_t* regA  = (ushort_t*)base;                   // aggX/t2/t3/t4
    ushort_t* regBC = (ushort_t*)(base + R50);           // h1 -> h2 -> h3

    if (ws_size < (8u << 20) + 3 * R50) return;

    const float invN = 1.0f / (float)NN;
    const int NB = (NN + 255) / 256;                     // 196 scan blocks
    const int GW = (NN * 64 + 255) / 256;                // wave-per-node grids (12500)
    const int GM = (NN + 127) / 128;                     // 391

    // ---- CSR build (parallel scan) + W transposes ----
    (void)hipMemsetAsync(deg, 0, 2 * NN * sizeof(int), stream);  // deg + cnt
    deg_kernel<<<(NE + 255) / 256, 256, 0, stream>>>(dst, deg, NE);
    scan_reduce<<<NB, 256, 0, stream>>>(deg, bsum, dis, NN);
    scan_offsets<<<1, 256, 0, stream>>>(bsum, boff, rowstart, NB, NN);
    scan_final<<<NB, 256, 0, stream>>>(deg, boff, rowstart, NN);
    fill_kernel<<<(NE + 255) / 256, 256, 0, stream>>>(src, dst, rowstart, cnt, esrc, ew, dis, NE);
    wt_kernel<<<(512 * 128 + 255) / 256, 256, 0, stream>>>(W1, wt1, 128, 500, 128, 512);
    wt_kernel<<<(1024 * 512 + 255) / 256, 256, 0, stream>>>(W2, wt2, 500, 1000, 512, 1024);
    wt_kernel<<<(512 * 1024 + 255) / 256, 256, 0, stream>>>(W3, wt3, 1000, 500, 1024, 512);
    wt_kernel<<<(64 * 512 + 255) / 256, 256, 0, stream>>>(W4, wt4, 500, 50, 512, 64);

    // ---- Layer 1: aggX = A_hat x; h1 = elu(aggX W1 + b1) ----
    gather_x<<<GW, 256, 0, stream>>>(x, regA, rowstart, esrc, ew, dis, NN);
    mfma_gemm<ushort_t><<<dim3(GM, 8), 256, 0, stream>>>(
        regA, wt1, b1, nullptr, nullptr, regBC, NN, 128, 500, 512, 1);
    (void)hipMemsetAsync(sum, 0, 8192 * sizeof(float), stream);
    colstats_kernel<<<(NN + CS_ROWS - 1) / CS_ROWS, 256, 0, stream>>>(regBC, sum, sumsq, NN, 500, 512);
    bnparams_kernel<<<2, 256, 0, stream>>>(sum, sumsq, g1, be1, scale, shift, 500, 512, invN);

    // ---- Layer 2: t2 = A_hat bn(h1); h2 = elu(t2 W2 + b2) ----
    gather_b8<<<GW, 256, 0, stream>>>(
        regBC, regA, rowstart, esrc, ew, dis, scale, shift, nullptr, 500, 0, NN);
    mfma_gemm<ushort_t><<<dim3(GM, 16), 256, 0, stream>>>(
        regA, wt2, b2, nullptr, nullptr, regBC, NN, 512, 1000, 1024, 1);
    (void)hipMemsetAsync(sum, 0, 8192 * sizeof(float), stream);
    colstats_kernel<<<(NN + CS_ROWS - 1) / CS_ROWS, 256, 0, stream>>>(regBC, sum, sumsq, NN, 1000, 1024);
    bnparams_kernel<<<4, 256, 0, stream>>>(sum, sumsq, g2, be2, scale, shift, 1000, 1024, invN);

    // ---- Layer 3: t3 = bn(h2) W3; h3 = elu(A_hat t3 + b3) ----
    mfma_gemm<ushort_t><<<dim3(GM, 8), 256, 0, stream>>>(
        regBC, wt3, nullptr, scale, shift, regA, NN, 1024, 500, 512, 0);
    gather_b8<<<GW, 256, 0, stream>>>(
        regA, regBC, rowstart, esrc, ew, dis, nullptr, nullptr, b3, 500, 1, NN);
    (void)hipMemsetAsync(sum, 0, 8192 * sizeof(float), stream);
    colstats_kernel<<<(NN + CS_ROWS - 1) / CS_ROWS, 256, 0, stream>>>(regBC, sum, sumsq, NN, 500, 512);
    bnparams_kernel<<<2, 256, 0, stream>>>(sum, sumsq, g3, be3, scale, shift, 500, 512, invN);

    // ---- Layer 4: t4 = bn(h3) W4 (f32); out = A_hat t4 + b4 ----
    float* t4 = (float*)regA;
    mfma_gemm<float><<<dim3(GM, 1), 256, 0, stream>>>(
        regBC, wt4, nullptr, scale, shift, t4, NN, 512, 50, 64, 0);
    gather_out<<<GW, 256, 0, stream>>>(t4, out, rowstart, esrc, ew, dis, b4, NN);
}